// Round 8
// baseline (446.653 us; speedup 1.0000x reference)
//
#include <hip/hip_runtime.h>

typedef __attribute__((ext_vector_type(8))) short short8;
typedef __attribute__((ext_vector_type(4))) float f32x4;

__device__ __forceinline__ float bf2f(unsigned short u){
  return __uint_as_float(((unsigned int)u) << 16);
}
__device__ __forceinline__ unsigned short f2bf(float f){
  unsigned int u = __float_as_uint(f);
  u += 0x7fffu + ((u >> 16) & 1u);   // RNE
  return (unsigned short)(u >> 16);
}
// dtype-dispatching scalar load: isF32 ? f32[i] : bf16[i]
__device__ __forceinline__ float ldf(const void* p, long i, int isF32){
  return isF32 ? ((const float*)p)[i] : bf2f(((const unsigned short*)p)[i]);
}

// ---- prep: dtype detect (block 0) + row_ptr from sorted rows ----
__global__ void prep_k(const int* __restrict__ rows, int* __restrict__ rs,
                       int E, int N, const unsigned short* __restrict__ x,
                       int* __restrict__ flag){
  if (blockIdx.x == 0){
    __shared__ int s;
    if (threadIdx.x == 0) s = 0;
    __syncthreads();
    int bad = 0;
    for (int i = threadIdx.x; i < 2048; i += 256){
      unsigned int e = ((unsigned int)x[2 * i] >> 7) & 0xffu;
      if (e >= 0xF0u) bad = 1;
    }
    if (bad) atomicOr(&s, 1);
    __syncthreads();
    if (threadIdx.x == 0) *flag = s;
  }
  int e = blockIdx.x * 256 + threadIdx.x;
  if (e >= E) return;
  if (e == 0){
    for (int r = 0; r <= rows[0]; ++r) rs[r] = 0;
  } else {
    int a = rows[e - 1], b = rows[e];
    for (int r = a + 1; r <= b; ++r) rs[r] = e;
  }
  if (e == E - 1){
    for (int r = rows[E - 1] + 1; r <= N; ++r) rs[r] = E;
  }
}

// ---- fused transpose of all three W matrices -> canonical bf16 WT ----
__global__ void wtrans_all(const void* __restrict__ Wres,
                           const void* __restrict__ W1,
                           const void* __restrict__ W2,
                           unsigned short* __restrict__ WresT,
                           unsigned short* __restrict__ W1T,
                           unsigned short* __restrict__ W2T,
                           const int* __restrict__ flag){
  int isF32 = *flag;
  int b = blockIdx.x;
  const void* W; unsigned short* WT; int K; int idx;
  if (b < 128)      { W = Wres; WT = WresT; K = 256; idx = b * 256 + threadIdx.x; }
  else if (b < 256) { W = W1;   WT = W1T;   K = 256; idx = (b - 128) * 256 + threadIdx.x; }
  else              { W = W2;   WT = W2T;   K = 128; idx = (b - 256) * 256 + threadIdx.x; }
  if (idx >= K * 128) return;
  int n = idx / K, k = idx - n * K;
  WT[idx] = f2bf(ldf(W, (long)k * 128 + n, isF32));
}

// ============================================================
// Fused dual GEMM (R2-measured 117us structure): z = x@Wres+bres,
// y1 = x@W1, both bf16 out, one A-read.  2 waves/SIMD.
// ============================================================
__global__ __launch_bounds__(256, 2) void gemm_zy1(
    const void* __restrict__ A,
    const unsigned short* __restrict__ WT0,  // WresT [128][256]
    const unsigned short* __restrict__ WT1,  // W1T   [128][256]
    const void* __restrict__ bias0,
    unsigned short* __restrict__ out0,       // z  [M][128] bf16
    unsigned short* __restrict__ out1,       // y1 [M][128] bf16
    int M, const int* __restrict__ flagp)
{
  constexpr int K = 256, KB = 128;
  __shared__ __align__(16) unsigned short lW[2 * 128 * 128];  // 64 KB

  const int fl   = *flagp;
  const int tid  = threadIdx.x;
  const int lane = tid & 63;
  const int wav  = tid >> 6;
  const int l16  = lane & 15;
  const int quad = lane >> 4;
  const int rowBase = blockIdx.x * 128 + wav * 32;

  f32x4 acc[2][2][8];   // [plane][s][nt]
#pragma unroll
  for (int w = 0; w < 2; ++w)
#pragma unroll
    for (int s = 0; s < 2; ++s)
#pragma unroll
      for (int nt = 0; nt < 8; ++nt) acc[w][s][nt] = (f32x4){0.f, 0.f, 0.f, 0.f};

  for (int kb = 0; kb < K; kb += KB){
    __syncthreads();
#pragma unroll
    for (int i = tid; i < 2 * 128 * 16; i += 256){
      int t = i >> 11;
      int j = i & 2047;
      int n = j >> 4;
      int c = j & 15;
      const unsigned short* WT = t ? WT1 : WT0;
      *(short8*)&lW[(t * 128 + n) * 128 + ((c * 8) ^ ((n & 7) * 8))] =
          *(const short8*)&WT[n * K + kb + c * 8];
    }
    short8 af[2][4];
    if (fl){
#pragma unroll
      for (int s = 0; s < 2; ++s){
        int r = rowBase + s * 16 + l16;
        const float* Af = (const float*)A + (long)r * K + kb + quad * 8;
        f32x4 t0[4], t1[4];
#pragma unroll
        for (int q = 0; q < 4; ++q){
          if (r < M){
            t0[q] = *(const f32x4*)(Af + q * 32);
            t1[q] = *(const f32x4*)(Af + q * 32 + 4);
          } else {
            t0[q] = (f32x4){0.f, 0.f, 0.f, 0.f};
            t1[q] = (f32x4){0.f, 0.f, 0.f, 0.f};
          }
        }
#pragma unroll
        for (int q = 0; q < 4; ++q){
          short8 v;
          v[0] = (short)f2bf(t0[q][0]); v[1] = (short)f2bf(t0[q][1]);
          v[2] = (short)f2bf(t0[q][2]); v[3] = (short)f2bf(t0[q][3]);
          v[4] = (short)f2bf(t1[q][0]); v[5] = (short)f2bf(t1[q][1]);
          v[6] = (short)f2bf(t1[q][2]); v[7] = (short)f2bf(t1[q][3]);
          af[s][q] = v;
        }
      }
    } else {
#pragma unroll
      for (int s = 0; s < 2; ++s){
        int r = rowBase + s * 16 + l16;
        const unsigned short* Ab = (const unsigned short*)A + (long)r * K + kb + quad * 8;
#pragma unroll
        for (int q = 0; q < 4; ++q){
          short8 v = {};
          if (r < M) v = *(const short8*)(Ab + q * 32);
          af[s][q] = v;
        }
      }
    }
    __syncthreads();
#pragma unroll
    for (int q = 0; q < 4; ++q){
#pragma unroll
      for (int nt = 0; nt < 8; ++nt){
        int row = nt * 16 + l16;
        int bo  = row * 128 + ((q * 32 + quad * 8) ^ ((row & 7) * 8));
        short8 b0 = *(const short8*)&lW[bo];
        short8 b1 = *(const short8*)&lW[128 * 128 + bo];
        acc[0][0][nt] = __builtin_amdgcn_mfma_f32_16x16x32_bf16(af[0][q], b0, acc[0][0][nt], 0, 0, 0);
        acc[0][1][nt] = __builtin_amdgcn_mfma_f32_16x16x32_bf16(af[1][q], b0, acc[0][1][nt], 0, 0, 0);
        acc[1][0][nt] = __builtin_amdgcn_mfma_f32_16x16x32_bf16(af[0][q], b1, acc[1][0][nt], 0, 0, 0);
        acc[1][1][nt] = __builtin_amdgcn_mfma_f32_16x16x32_bf16(af[1][q], b1, acc[1][1][nt], 0, 0, 0);
      }
    }
  }

#pragma unroll
  for (int s = 0; s < 2; ++s){
    int r0 = rowBase + s * 16 + quad * 4;
#pragma unroll
    for (int nt = 0; nt < 8; ++nt){
      int col = nt * 16 + l16;
      float bv = ldf(bias0, col, fl);
#pragma unroll
      for (int rg = 0; rg < 4; ++rg){
        int r = r0 + rg;
        if (r < M){
          out0[(long)r * 128 + col] = f2bf(acc[0][s][nt][rg] + bv);   // z
          out1[(long)r * 128 + col] = f2bf(acc[1][s][nt][rg]);        // y1
        }
      }
    }
  }
}

// ============================================================
// y2 GEMM (R2 structure): y2 = x1(bf16)@W2, bf16 out.
// ============================================================
__global__ __launch_bounds__(256, 3) void gemm_y2(
    const unsigned short* __restrict__ A,    // x1 bf16 [M][128]
    const unsigned short* __restrict__ WT,   // W2T [128][128]
    unsigned short* __restrict__ out,        // y2 bf16 [M][128]
    int M)
{
  constexpr int K = 128;
  __shared__ __align__(16) unsigned short lW[128 * 128];   // 32 KB

  const int tid  = threadIdx.x;
  const int lane = tid & 63;
  const int wav  = tid >> 6;
  const int l16  = lane & 15;
  const int quad = lane >> 4;
  const int rowBase = blockIdx.x * 128 + wav * 32;

#pragma unroll
  for (int i = tid; i < 128 * 16; i += 256){
    int n = i >> 4;
    int c = i & 15;
    *(short8*)&lW[n * 128 + ((c * 8) ^ ((n & 7) * 8))] = *(const short8*)&WT[n * K + c * 8];
  }
  short8 af[2][4];
#pragma unroll
  for (int s = 0; s < 2; ++s){
    int r = rowBase + s * 16 + l16;
    const unsigned short* Ab = A + (long)r * K + quad * 8;
#pragma unroll
    for (int q = 0; q < 4; ++q){
      short8 v = {};
      if (r < M) v = *(const short8*)(Ab + q * 32);
      af[s][q] = v;
    }
  }
  f32x4 acc[2][8];
#pragma unroll
  for (int s = 0; s < 2; ++s)
#pragma unroll
    for (int nt = 0; nt < 8; ++nt) acc[s][nt] = (f32x4){0.f, 0.f, 0.f, 0.f};
  __syncthreads();
#pragma unroll
  for (int q = 0; q < 4; ++q){
#pragma unroll
    for (int nt = 0; nt < 8; ++nt){
      int row = nt * 16 + l16;
      short8 b = *(const short8*)&lW[row * 128 + ((q * 32 + quad * 8) ^ ((row & 7) * 8))];
      acc[0][nt] = __builtin_amdgcn_mfma_f32_16x16x32_bf16(af[0][q], b, acc[0][nt], 0, 0, 0);
      acc[1][nt] = __builtin_amdgcn_mfma_f32_16x16x32_bf16(af[1][q], b, acc[1][nt], 0, 0, 0);
    }
  }
#pragma unroll
  for (int s = 0; s < 2; ++s){
    int r0 = rowBase + s * 16 + quad * 4;
#pragma unroll
    for (int nt = 0; nt < 8; ++nt){
      int col = nt * 16 + l16;
#pragma unroll
      for (int rg = 0; rg < 4; ++rg){
        int r = r0 + rg;
        if (r < M) out[(long)r * 128 + col] = f2bf(acc[s][nt][rg]);
      }
    }
  }
}

// ============================================================
// 4-edges-per-instruction gather: 16 lanes/edge x 16B (dwordx4).
// lane = 16*eo + f: edge-group eo in [0,4), feature slot f in
// [0,16) covering features [8f,8f+8).  3 VMEM instr / 4 edges
// (vs 12 in the 1-edge/gather form).  Tail via exec-mask
// predication (no address clamping -> no padded traffic).
// ============================================================
template<int FL>
__device__ __forceinline__ void row_gather4(
    int e0, int e1, const int* __restrict__ cols, const void* __restrict__ vals,
    const unsigned short* __restrict__ Y, int eo, int f, float* acc)
{
  const unsigned short* Yf = Y + f * 8;
  for (int eb = e0; eb < e1; eb += 8){      // 2 groups of 4 per iter (MLP)
    int ea = eb + eo;
    int eb2 = eb + 4 + eo;
    bool va = ea < e1, vb = eb2 < e1;
    int ca = 0, cb = 0; float fa = 0.f, fb = 0.f;
    if (va){
      ca = cols[ea];
      fa = FL ? ((const float*)vals)[ea] : bf2f(((const unsigned short*)vals)[ea]);
    }
    if (vb){
      cb = cols[eb2];
      fb = FL ? ((const float*)vals)[eb2] : bf2f(((const unsigned short*)vals)[eb2]);
    }
    uint4 qa = make_uint4(0u, 0u, 0u, 0u), qb = make_uint4(0u, 0u, 0u, 0u);
    if (va) qa = *(const uint4*)(Yf + (long)ca * 128);
    if (vb) qb = *(const uint4*)(Yf + (long)cb * 128);
    acc[0] = fmaf(fa, bf2f((unsigned short)(qa.x & 0xffffu)), acc[0]);
    acc[1] = fmaf(fa, bf2f((unsigned short)(qa.x >> 16)),     acc[1]);
    acc[2] = fmaf(fa, bf2f((unsigned short)(qa.y & 0xffffu)), acc[2]);
    acc[3] = fmaf(fa, bf2f((unsigned short)(qa.y >> 16)),     acc[3]);
    acc[4] = fmaf(fa, bf2f((unsigned short)(qa.z & 0xffffu)), acc[4]);
    acc[5] = fmaf(fa, bf2f((unsigned short)(qa.z >> 16)),     acc[5]);
    acc[6] = fmaf(fa, bf2f((unsigned short)(qa.w & 0xffffu)), acc[6]);
    acc[7] = fmaf(fa, bf2f((unsigned short)(qa.w >> 16)),     acc[7]);
    acc[0] = fmaf(fb, bf2f((unsigned short)(qb.x & 0xffffu)), acc[0]);
    acc[1] = fmaf(fb, bf2f((unsigned short)(qb.x >> 16)),     acc[1]);
    acc[2] = fmaf(fb, bf2f((unsigned short)(qb.y & 0xffffu)), acc[2]);
    acc[3] = fmaf(fb, bf2f((unsigned short)(qb.y >> 16)),     acc[3]);
    acc[4] = fmaf(fb, bf2f((unsigned short)(qb.z & 0xffffu)), acc[4]);
    acc[5] = fmaf(fb, bf2f((unsigned short)(qb.z >> 16)),     acc[5]);
    acc[6] = fmaf(fb, bf2f((unsigned short)(qb.w & 0xffffu)), acc[6]);
    acc[7] = fmaf(fb, bf2f((unsigned short)(qb.w >> 16)),     acc[7]);
  }
  // combine the 4 edge-groups: lanes with equal f differ in bits 4,5
#pragma unroll
  for (int j = 0; j < 8; ++j){
    acc[j] += __shfl_xor(acc[j], 16);
    acc[j] += __shfl_xor(acc[j], 32);
  }
}

// ---- spmm1: x1[r] = relu(agg(y1)[r] + b1) + z[r], bf16 out ----
__global__ __launch_bounds__(256) void spmm1_g(
    const int* __restrict__ rs, const int* __restrict__ cols,
    const void* __restrict__ vals, const unsigned short* __restrict__ Y,
    const unsigned short* __restrict__ z, const void* __restrict__ b1,
    unsigned short* __restrict__ x1, int N, const int* __restrict__ flagp)
{
  const int fl   = *flagp;
  const int lane = threadIdx.x & 63;
  const int wav  = threadIdx.x >> 6;
  int r = blockIdx.x * 4 + wav;
  if (r >= N) return;
  int e0 = __builtin_amdgcn_readfirstlane(rs[r]);
  int e1 = __builtin_amdgcn_readfirstlane(rs[r + 1]);
  const int eo = lane >> 4;
  const int f  = lane & 15;
  float acc[8];
#pragma unroll
  for (int j = 0; j < 8; ++j) acc[j] = 0.f;
  if (fl) row_gather4<1>(e0, e1, cols, vals, Y, eo, f, acc);
  else    row_gather4<0>(e0, e1, cols, vals, Y, eo, f, acc);
  if (eo == 0){
    long o = (long)r * 128 + f * 8;
    uint4 zz = *(const uint4*)&z[o];
    unsigned int zw[4] = {zz.x, zz.y, zz.z, zz.w};
    unsigned int ow[4];
#pragma unroll
    for (int j = 0; j < 4; ++j){
      float blo = ldf(b1, f * 8 + 2 * j,     fl);
      float bhi = ldf(b1, f * 8 + 2 * j + 1, fl);
      float lo = fmaxf(acc[2 * j]     + blo, 0.f) + bf2f((unsigned short)(zw[j] & 0xffffu));
      float hi = fmaxf(acc[2 * j + 1] + bhi, 0.f) + bf2f((unsigned short)(zw[j] >> 16));
      ow[j] = (unsigned int)f2bf(lo) | ((unsigned int)f2bf(hi) << 16);
    }
    uint4 w; w.x = ow[0]; w.y = ow[1]; w.z = ow[2]; w.w = ow[3];
    *(uint4*)&x1[o] = w;
  }
}

// ---- spmm2: out[r] = log_softmax(agg(y2)[r] + b2), dtype per flag ----
__global__ __launch_bounds__(256) void spmm2_g(
    const int* __restrict__ rs, const int* __restrict__ cols,
    const void* __restrict__ vals, const unsigned short* __restrict__ Y,
    const void* __restrict__ b2, void* __restrict__ out, int N,
    const int* __restrict__ flagp)
{
  const int fl   = *flagp;
  const int lane = threadIdx.x & 63;
  const int wav  = threadIdx.x >> 6;
  int r = blockIdx.x * 4 + wav;
  if (r >= N) return;
  int e0 = __builtin_amdgcn_readfirstlane(rs[r]);
  int e1 = __builtin_amdgcn_readfirstlane(rs[r + 1]);
  const int eo = lane >> 4;
  const int f  = lane & 15;
  float acc[8];
#pragma unroll
  for (int j = 0; j < 8; ++j) acc[j] = 0.f;
  if (fl) row_gather4<1>(e0, e1, cols, vals, Y, eo, f, acc);
  else    row_gather4<0>(e0, e1, cols, vals, Y, eo, f, acc);
  float v[8];
#pragma unroll
  for (int j = 0; j < 8; ++j) v[j] = acc[j] + ldf(b2, f * 8 + j, fl);
  float m = v[0];
#pragma unroll
  for (int j = 1; j < 8; ++j) m = fmaxf(m, v[j]);
#pragma unroll
  for (int off = 1; off <= 8; off <<= 1) m = fmaxf(m, __shfl_xor(m, off));
  float s = 0.f;
#pragma unroll
  for (int j = 0; j < 8; ++j) s += expf(v[j] - m);
#pragma unroll
  for (int off = 1; off <= 8; off <<= 1) s += __shfl_xor(s, off);
  float lse = m + logf(s);
  if (eo == 0){
    long o = (long)r * 128 + f * 8;
    if (fl){
      float* op = (float*)out + o;
      f32x4 w0, w1;
#pragma unroll
      for (int j = 0; j < 4; ++j){ w0[j] = v[j] - lse; w1[j] = v[4 + j] - lse; }
      *(f32x4*)op = w0;
      *(f32x4*)(op + 4) = w1;
    } else {
      unsigned int ow[4];
#pragma unroll
      for (int j = 0; j < 4; ++j)
        ow[j] = (unsigned int)f2bf(v[2 * j] - lse) |
                ((unsigned int)f2bf(v[2 * j + 1] - lse) << 16);
      uint4 w; w.x = ow[0]; w.y = ow[1]; w.z = ow[2]; w.w = ow[3];
      *(uint4*)&((unsigned short*)out)[o] = w;
    }
  }
}

extern "C" void kernel_launch(void* const* d_in, const int* in_sizes, int n_in,
                              void* d_out, int out_size, void* d_ws, size_t ws_size,
                              hipStream_t stream)
{
  const void* x    = d_in[0];
  const int*  erow = (const int*)d_in[1];
  const int*  ecol = (const int*)d_in[2];
  const void* eval = d_in[3];
  const void* Wres = d_in[4];
  const void* bres = d_in[5];
  const void* W1   = d_in[6];
  const void* b1   = d_in[7];
  const void* W2   = d_in[8];
  const void* b2   = d_in[9];
  const int N = in_sizes[0] / 256;   // 100000
  const int E = in_sizes[1];         // 1600000

  char* ws = (char*)d_ws;
  size_t szB = (size_t)N * 128 * 2;  // one bf16 [N,128] plane (25.6 MB)
  unsigned short* bufA  = (unsigned short*)ws;            // y1, then y2
  unsigned short* bufC  = (unsigned short*)(ws + szB);    // x1
  unsigned short* WresT = (unsigned short*)(ws + 2 * szB);
  unsigned short* W1T   = WresT + 256 * 128;
  unsigned short* W2T   = W1T   + 256 * 128;
  int*            flag  = (int*)(W2T + 256 * 128);
  int*            rs    = flag + 4;                        // [N+1] row_ptr
  unsigned short* zbuf  = (unsigned short*)d_out;          // z (bf16) in d_out

  prep_k<<<(E + 255) / 256, 256, 0, stream>>>(erow, rs, E, N,
                                              (const unsigned short*)x, flag);
  wtrans_all<<<320, 256, 0, stream>>>(Wres, W1, W2, WresT, W1T, W2T, flag);

  const int gBlocks = (N + 127) / 128;
  const int rBlocks = (N + 3) / 4;

  gemm_zy1<<<gBlocks, 256, 0, stream>>>(x, WresT, W1T, bres, zbuf, bufA, N, flag); // z + y1

  spmm1_g<<<rBlocks, 256, 0, stream>>>(rs, ecol, eval, bufA, zbuf, b1, bufC, N, flag); // x1

  gemm_y2<<<gBlocks, 256, 0, stream>>>(bufC, W2T, bufA, N);                            // y2

  spmm2_g<<<rBlocks, 256, 0, stream>>>(rs, ecol, eval, bufA, b2, d_out, N, flag);      // out
}